// Round 7
// baseline (353.074 us; speedup 1.0000x reference)
//
#include <hip/hip_runtime.h>
#include <hip/hip_bf16.h>
#include <cstdint>
#include <cstddef>

#define D_MODEL   1024
#define D_INNER   2048
#define D_STATE   64
#define HEADDIM   128
#define NHEADS    16
#define D_CONV    4
#define CHUNK     256
#define D_IN_PROJ 4240     // 2*D_INNER + 2*D_STATE + NHEADS
#define ZPAD      4352     // padded for MFMA tiles
#define CONV_DIM  2176     // D_INNER + 2*D_STATE
#define NB        2
#define LEN       4096
#define NC        16
#define MROWS     (NB*LEN) // 8192

typedef __hip_bfloat16 bf16;
typedef __bf16 bf16x8 __attribute__((ext_vector_type(8)));
typedef float  f32x4  __attribute__((ext_vector_type(4)));
typedef unsigned short us4 __attribute__((ext_vector_type(4)));

__device__ __forceinline__ float fsilu(float x){ return x / (1.f + __expf(-x)); }
__device__ __forceinline__ float toF(float x){ return x; }
__device__ __forceinline__ float toF(bf16 x){ return __bfloat162float(x); }

__device__ __forceinline__ unsigned short f2bs(float v){
  return __bfloat16_as_ushort(__float2bfloat16(v));
}
__device__ __forceinline__ void store4(bf16* p, f32x4 v){
  us4 o; o[0]=f2bs(v[0]); o[1]=f2bs(v[1]); o[2]=f2bs(v[2]); o[3]=f2bs(v[3]);
  *(us4*)p = o;
}
__device__ __forceinline__ void store4(float* p, f32x4 v){
  *(f32x4*)p = v;
}

__device__ __forceinline__ void gload_lds16(const void* g, void* l){
  __builtin_amdgcn_global_load_lds(
     (const __attribute__((address_space(1))) unsigned int*)(uintptr_t)g,
     (__attribute__((address_space(3))) unsigned int*)(uintptr_t)l, 16, 0, 0);
}

// ---------------------------------------------------------------------------
// MFMA bf16 GEMM (round-6 champion, unchanged): C[m,n] = sum_k A[m,k]*B[n,k]
// BK=64, 2x32KB double buffer, counted vmcnt(4), 512 thr = 8 waves (2M x 4N,
// 64x32/wave), sigma(row)=row&7 both-sides swizzle (0 conflicts), plain 2D
// grid m-fastest (per-XCD A slice L2-resident, ~62MB FETCH).
// Measured: 92.4us GEMM1, MfmaUtil 34%, occ 36%.  LDS-BW arithmetic: reads
// 2x96KB + writes 2x32KB per CU-iter ~ 750cy vs 310cy matrix -> ~41% util
// cap; structure is near its ceiling.
// ---------------------------------------------------------------------------
template<typename TC>
__global__ __launch_bounds__(512) void k_gemm_8w(
    const bf16* __restrict__ A, int lda,
    const bf16* __restrict__ B, int ldb,
    TC* __restrict__ C, int ldc, int K)
{
  __shared__ __align__(16) __bf16 As[2][128*64];   // 16KB per buffer
  __shared__ __align__(16) __bf16 Bs[2][128*64];
  const int tid  = threadIdx.x;
  const int w    = tid >> 6, l = tid & 63;
  const int quad = l >> 4, lq = l & 15;
  const int wm   = (w & 1)*64;        // 2 M-wave positions (64 rows)
  const int wn   = (w >> 1)*32;       // 4 N-wave positions (32 rows)
  const int m0 = blockIdx.x*128, n0 = blockIdx.y*128;

  // staging source map (chunk = tid on instr0, row +64 on instr1)
  const int sr = tid >> 3;                         // row 0..63
  const int sc = ((tid & 7) ^ (sr & 7)) * 8;       // element col (16B slots)
  const bf16* Ag = A + (size_t)(m0 + sr)*lda + sc;
  const bf16* Bg = B + (size_t)(n0 + sr)*ldb + sc;
  const int sdo = w*1024;                          // wave-uniform LDS offset

  auto stage = [&](int t, int buf){
    const int k0 = t*64;
    char* ab = (char*)&As[buf][0] + sdo;
    char* bb = (char*)&Bs[buf][0] + sdo;
    gload_lds16(Ag + k0,                  ab);
    gload_lds16(Ag + (size_t)64*lda + k0, ab + 8192);
    gload_lds16(Bg + k0,                  bb);
    gload_lds16(Bg + (size_t)64*ldb + k0, bb + 8192);
  };

  f32x4 acc[4][2] = {};

  stage(0, 0);
  const int NT = K >> 6;
  for (int t = 0; t < NT; ++t){
    const int cur = t & 1;
    if (t+1 < NT){
      stage(t+1, cur^1);
      asm volatile("s_waitcnt vmcnt(4)" ::: "memory");   // tile t's 4 landed
    } else {
      asm volatile("s_waitcnt vmcnt(0)" ::: "memory");
    }
    asm volatile("s_barrier" ::: "memory");

    const char* Ab = (const char*)&As[cur][0];
    const char* Bb = (const char*)&Bs[cur][0];
    #pragma unroll
    for (int s=0;s<2;s++){
      const int slot = (((s*4 + quad) ^ (lq & 7)) << 4);
      bf16x8 af[4], bfr[2];
      #pragma unroll
      for (int tm=0;tm<4;tm++)
        af[tm]  = *(const bf16x8*)(Ab + (wm + tm*16 + lq)*128 + slot);
      #pragma unroll
      for (int tn=0;tn<2;tn++)
        bfr[tn] = *(const bf16x8*)(Bb + (wn + tn*16 + lq)*128 + slot);
      #pragma unroll
      for (int tm=0;tm<4;tm++)
        #pragma unroll
        for (int tn=0;tn<2;tn++)
          acc[tm][tn] = __builtin_amdgcn_mfma_f32_16x16x32_bf16(bfr[tn], af[tm], acc[tm][tn], 0,0,0);
    }
    asm volatile("s_barrier" ::: "memory");   // reads of cur done before t+2 stages into it
  }

  #pragma unroll
  for (int tm = 0; tm < 4; tm++){
    int r = m0 + wm + tm*16 + lq;
    #pragma unroll
    for (int tn = 0; tn < 2; tn++){
      int cb = n0 + wn + tn*16 + quad*4;
      store4(&C[(size_t)r*ldc + cb], acc[tm][tn]);
    }
  }
}

// ---------------------------------------------------------------------------
// Fused conversions: u->ub ; in_proj_w->Wb_in (padded) ; out_proj_w*norm_w->Wb_out
// ---------------------------------------------------------------------------
#define NU4  (MROWS*D_MODEL/4)
#define NW14 (ZPAD*D_MODEL/4)
#define NW24 (D_MODEL*D_INNER/4)
__global__ __launch_bounds__(256) void k_convert(
    const float* __restrict__ u, const float* __restrict__ Win,
    const float* __restrict__ Wout, const float* __restrict__ norm_w,
    bf16* __restrict__ ub, bf16* __restrict__ Wb_in, bf16* __restrict__ Wb_out){
  int i4 = blockIdx.x*256 + threadIdx.x;
  if (i4 < NU4){
    float4 v = ((const float4*)u)[i4];
    us4 o = {f2bs(v.x), f2bs(v.y), f2bs(v.z), f2bs(v.w)};
    ((us4*)ub)[i4] = o;
  } else if (i4 < NU4 + NW14){
    int j = i4 - NU4;
    int r = j >> 8;
    float4 v = make_float4(0.f,0.f,0.f,0.f);
    if (r < D_IN_PROJ) v = ((const float4*)Win)[j];
    us4 o = {f2bs(v.x), f2bs(v.y), f2bs(v.z), f2bs(v.w)};
    ((us4*)Wb_in)[j] = o;
  } else {
    int j = i4 - NU4 - NW14;
    float4 v = ((const float4*)Wout)[j];
    float4 nw = ((const float4*)norm_w)[j & 511];
    us4 o = {f2bs(v.x*nw.x), f2bs(v.y*nw.y), f2bs(v.z*nw.z), f2bs(v.w*nw.w)};
    ((us4*)Wb_out)[j] = o;
  }
}

// ---------------------------------------------------------------------------
// dt = softplus(dt_raw + dt_bias); a = dt*A; inclusive cumsum over chunk.
// ---------------------------------------------------------------------------
__global__ __launch_bounds__(256) void k_dt(
    const bf16* __restrict__ zxbct, const float* __restrict__ dt_bias,
    const float* __restrict__ A_log, float* __restrict__ dt_t,
    float* __restrict__ acum_t, float* __restrict__ cd_t){
  int bid = blockIdx.x;
  int h = bid & 15, c = (bid>>4)&15, b = bid>>8;
  int q = threadIdx.x;
  size_t m = (size_t)(b*NC + c)*CHUNK + q;
  float x = toF(zxbct[m*ZPAD + (D_INNER + CONV_DIM) + h]) + dt_bias[h];
  float dtv = (x > 20.f) ? x : log1pf(__expf(x));
  float Ah = -__expf(A_log[h]);
  float a = dtv * Ah;
  __shared__ float sb[CHUNK];
  sb[q] = a;
  __syncthreads();
  #pragma unroll
  for (int off=1; off<CHUNK; off<<=1){
    float t = (q >= off) ? sb[q-off] : 0.f;
    __syncthreads();
    sb[q] += t;
    __syncthreads();
  }
  float ac = sb[q];
  size_t o = ((size_t)(b*NHEADS+h))*LEN + c*CHUNK + q;
  dt_t[o]   = dtv;
  acum_t[o] = ac;
  if (q == CHUNK-1) cd_t[(b*NHEADS+h)*NC + c] = __expf(ac);
}

// ---------------------------------------------------------------------------
// Depthwise causal conv (4 taps) + SiLU, LDS-staged.  64 ch x 64 rows/block.
// ---------------------------------------------------------------------------
__global__ __launch_bounds__(256) void k_conv(
    const bf16* __restrict__ zxbct, const float* __restrict__ conv_w,
    const float* __restrict__ conv_b, bf16* __restrict__ xbc){
  __shared__ __align__(16) __bf16 xs[67*64];
  __shared__ __align__(16) float  ws[64*4];
  __shared__ float bs[64];
  const int tid = threadIdx.x;
  const int cq = tid & 7;
  const int tm = tid >> 3;          // 0..31
  const int c0 = blockIdx.x*64;
  const int m0 = blockIdx.y*64;
  {
    int g = m0 - 3 + tm; if (g < 0) g = 0;
    *(bf16x8*)&xs[tm*64 + cq*8] =
        *(const bf16x8*)(zxbct + (size_t)g*ZPAD + D_INNER + c0 + cq*8);
    int g2 = m0 - 3 + tm + 32;
    *(bf16x8*)&xs[(tm+32)*64 + cq*8] =
        *(const bf16x8*)(zxbct + (size_t)g2*ZPAD + D_INNER + c0 + cq*8);
    if (tid < 24){
      int r3 = 64 + (tid >> 3);
      int g3 = m0 - 3 + r3;
      *(bf16x8*)&xs[r3*64 + cq*8] =
          *(const bf16x8*)(zxbct + (size_t)g3*ZPAD + D_INNER + c0 + cq*8);
    }
  }
  if (tid < 64)      *(float4*)&ws[tid*4] = *(const float4*)(conv_w + (size_t)(c0+tid)*4);
  else if (tid < 128) bs[tid-64] = conv_b[c0 + tid - 64];
  __syncthreads();

  #pragma unroll
  for (int rr=0; rr<2; rr++){
    const int r = tm + rr*32;
    const int m = m0 + r;
    const int l = m & (LEN-1);
    float acc[8];
    #pragma unroll
    for (int j=0;j<8;j++) acc[j] = bs[cq*8+j];
    #pragma unroll
    for (int w=0; w<D_CONV; w++){
      if (l - (D_CONV-1) + w >= 0){
        bf16x8 v = *(const bf16x8*)&xs[(r+w)*64 + cq*8];
        #pragma unroll
        for (int j=0;j<8;j++) acc[j] += (float)v[j] * ws[(cq*8+j)*4 + w];
      }
    }
    bf16x8 o;
    #pragma unroll
    for (int j=0;j<8;j++) o[j] = (__bf16)fsilu(acc[j]);
    *(bf16x8*)(xbc + (size_t)m*CONV_DIM + c0 + cq*8) = o;
  }
}

// ---------------------------------------------------------------------------
// k_states per (b,c,h): states[p,n] = sum_q dt[q]*exp(alast-acum[q])*x[q,p]*B[q,n]
// Double-buffered transposed staging, 1 barrier per k-tile.
// ---------------------------------------------------------------------------
__global__ __launch_bounds__(256,2) void k_states(
    const bf16* __restrict__ xbc, const float* __restrict__ acum_t,
    const float* __restrict__ dt_t, float* __restrict__ states)
{
  const int bid = blockIdx.x;
  const int h = bid & 15, c = (bid>>4)&15, b = bid>>8;
  const int z = b*NC + c;
  const int tid = threadIdx.x;
  const int w = tid >> 6, l = tid & 63;
  const int quad = l >> 4, lq = l & 15;

  __shared__ __align__(16) __bf16 xsT[2][128*72];
  __shared__ __align__(16) __bf16 bts[2][64*72];

  const float* acum = acum_t + ((size_t)(b*NHEADS+h))*LEN + c*CHUNK;
  const float* dtc  = dt_t   + ((size_t)(b*NHEADS+h))*LEN + c*CHUNK;
  const float alast = acum[CHUNK-1];
  const bf16* xrow = xbc + (size_t)z*CHUNK*CONV_DIM + h*HEADDIM;
  const bf16* Brow = xbc + (size_t)z*CHUNK*CONV_DIM + D_INNER;

  f32x4 Sst[2][4] = {};

  auto stage = [&](int t, int buf){
    const int k0 = t*64;
    const bf16* xr = xrow + (size_t)(k0+l)*CONV_DIM;
    #pragma unroll
    for (int pass=0; pass<4; pass++){
      int pb = w*8 + pass*32;
      bf16x8 v = *(const bf16x8*)(xr + pb);
      #pragma unroll
      for (int j=0;j<8;j++) xsT[buf][(pb+j)*72 + l] = v[j];
    }
    float wl = dtc[k0+l] * __expf(alast - acum[k0+l]);
    const bf16* br = Brow + (size_t)(k0+l)*CONV_DIM;
    #pragma unroll
    for (int pass=0; pass<2; pass++){
      int nb = w*8 + pass*32;
      bf16x8 v = *(const bf16x8*)(br + nb);
      #pragma unroll
      for (int j=0;j<8;j++) bts[buf][(nb+j)*72 + l] = (__bf16)((float)v[j] * wl);
    }
  };

  stage(0, 0);
  for (int t = 0; t < 4; t++){
    const int buf = t & 1;
    __syncthreads();
    if (t < 3) stage(t+1, buf^1);
    #pragma unroll
    for (int s=0;s<2;s++){
      bf16x8 a2[2];
      #pragma unroll
      for (int mi=0;mi<2;mi++)
        a2[mi] = *(const bf16x8*)&xsT[buf][(w*32 + mi*16 + lq)*72 + s*32 + quad*8];
      #pragma unroll
      for (int ni=0;ni<4;ni++){
        bf16x8 bb = *(const bf16x8*)&bts[buf][(ni*16+lq)*72 + s*32 + quad*8];
        #pragma unroll
        for (int mi=0;mi<2;mi++)
          Sst[mi][ni] = __builtin_amdgcn_mfma_f32_16x16x32_bf16(bb, a2[mi], Sst[mi][ni], 0,0,0);
      }
    }
  }

  float* so = states + (size_t)bid*HEADDIM*D_STATE;
  #pragma unroll
  for (int mi=0;mi<2;mi++){
    int pp = w*32 + mi*16 + lq;
    #pragma unroll
    for (int ni=0;ni<4;ni++)
      store4(&so[pp*D_STATE + ni*16 + quad*4], Sst[mi][ni]);
  }
}

// ---------------------------------------------------------------------------
// Inter-chunk scan: prevb[c] = bf16(carry); carry = carry*cd + states[c]
// ---------------------------------------------------------------------------
__global__ __launch_bounds__(256) void k_scan(
    const float* __restrict__ states, const float* __restrict__ cd_t,
    bf16* __restrict__ prevb){
  int b = blockIdx.x >> 4, h = blockIdx.x & 15;
  int pt = blockIdx.y;
  int tid = threadIdx.x;
  float carry[4] = {0.f,0.f,0.f,0.f};
  for (int c=0;c<NC;c++){
    size_t base = ((size_t)(b*256 + c*16 + h))*HEADDIM*D_STATE + (size_t)pt*1024;
    float cd = cd_t[(b*NHEADS+h)*NC + c];
    #pragma unroll
    for (int i=0;i<4;i++){
      size_t idx = base + (size_t)i*256 + tid;
      prevb[idx] = __float2bfloat16(carry[i]);
      carry[i] = carry[i]*cd + states[idx];
    }
  }
}

// ---------------------------------------------------------------------------
// FUSED per (b,c,h): y = y_off (from prevb) + y_diag (scores->coef->PV) + x*Dp.
// Single write of y.  Balanced causal split (wave w owns q half-tiles w, 7-w).
// Double-buffered x^T staging, 1 barrier per k-tile.
// Round 7: REVERTED the R5 C-fragment register hoist (cfh cost 32 VGPR ->
// measured +5us vs R4's per-t L1 re-reads); ADDED transcendental reduction:
// y_off row-exps hoisted out of the s-loop (8->4), coefficient exps factored
// exp(aq1-acs[kl]) = exp(aq0-acs[kl]) * exp(aq1-aq0) with per-half eD
// (16 -> 8+1 exps per kh; acum strictly decreasing -> both args <= 0, safe).
// ---------------------------------------------------------------------------
__global__ __launch_bounds__(256,2) void k_fused(
    const bf16* __restrict__ xbc, const float* __restrict__ acum_t,
    const float* __restrict__ dt_t, const float* __restrict__ Dp,
    const bf16* __restrict__ prevb, bf16* __restrict__ y)
{
  const int bid = blockIdx.x;
  const int h = bid & 15, c = (bid>>4)&15, b = bid>>8;
  const int z = b*NC + c;
  const int tid = threadIdx.x;
  const int w = tid >> 6, l = tid & 63;
  const int quad = l >> 4, lq = l & 15;

  __shared__ __align__(16) __bf16 xsT[2][128*72];   // [p][k64] double-buffered
  __shared__ __align__(16) __bf16 Ms[4][32*40];     // per-wave coef [q32][k32]
  __shared__ float acs[CHUNK], dts[CHUNK];

  const float* acum = acum_t + ((size_t)(b*NHEADS+h))*LEN + c*CHUNK;
  const float* dtc  = dt_t   + ((size_t)(b*NHEADS+h))*LEN + c*CHUNK;
  acs[tid] = acum[tid];
  dts[tid] = dtc[tid];

  const bf16* xrow = xbc + (size_t)z*CHUNK*CONV_DIM + h*HEADDIM;
  const bf16* Brow = xbc + (size_t)z*CHUNK*CONV_DIM + D_INNER;
  const bf16* Crow = xbc + (size_t)z*CHUNK*CONV_DIM + D_INNER + D_STATE;
  const bf16* pv   = prevb + (size_t)bid*HEADDIM*D_STATE;
  const float Dph = Dp[h];
  const int j0 = w, j1 = 7 - w;

  f32x4 Yacc[2][2][8] = {};   // [half][qm][pn]; lane: q=lq, p=quad*4+i

  auto stage = [&](int t, int buf){
    const bf16* xr = xrow + (size_t)(t*64+l)*CONV_DIM;
    #pragma unroll
    for (int pass=0; pass<4; pass++){
      int pb = w*8 + pass*32;
      bf16x8 v = *(const bf16x8*)(xr + pb);
      #pragma unroll
      for (int j=0;j<8;j++) xsT[buf][(pb+j)*72 + l] = v[j];
    }
  };

  stage(0, 0);
  __syncthreads();   // covers acs/dts too

  // ---- y_off: Yacc += mfma(prevb p-rows, exp(acum_q)*C q-rows)
  // row-exps hoisted (s-invariant): 4 instead of 8
  float eyo[2][2];
  #pragma unroll
  for (int half=0; half<2; half++){
    const int j = half ? j1 : j0;
    #pragma unroll
    for (int qm=0;qm<2;qm++)
      eyo[half][qm] = __expf(acs[j*32 + qm*16 + lq]);
  }
  #pragma unroll
  for (int s=0;s<2;s++){
    bf16x8 bp[8];
    #pragma unroll
    for (int pn=0;pn<8;pn++)
      bp[pn] = *(const bf16x8*)(pv + (pn*16+lq)*D_STATE + s*32 + quad*8);
    #pragma unroll
    for (int half=0; half<2; half++){
      const int j = half ? j1 : j0;
      #pragma unroll
      for (int qm=0;qm<2;qm++){
        int row = j*32 + qm*16 + lq;
        float e = eyo[half][qm];
        bf16x8 a = *(const bf16x8*)(Crow + (size_t)row*CONV_DIM + s*32 + quad*8);
        bf16x8 ae;
        #pragma unroll
        for (int jj=0;jj<8;jj++) ae[jj] = (__bf16)((float)a[jj] * e);
        #pragma unroll
        for (int pn=0;pn<8;pn++)
          Yacc[half][qm][pn] = __builtin_amdgcn_mfma_f32_16x16x32_bf16(bp[pn], ae, Yacc[half][qm][pn], 0,0,0);
      }
    }
  }

  for (int t = 0; t < 4; t++){
    const int buf = t & 1;
    if (t > 0) __syncthreads();
    if (t < 3) stage(t+1, buf^1);

    #pragma unroll
    for (int half=0; half<2; half++){
      const int j = half ? j1 : j0;
      if (2*t > j) continue;
      const int qbase = j*32;
      bf16x8 cf[2][2];   // [s][qm]  (per-t L1 re-read -- R4 form)
      #pragma unroll
      for (int s=0;s<2;s++)
        #pragma unroll
        for (int qm=0;qm<2;qm++)
          cf[s][qm] = *(const bf16x8*)(Crow + (size_t)(qbase+qm*16+lq)*CONV_DIM + s*32 + quad*8);
      const float aq0 = acs[qbase + lq];
      const float eD  = __expf(acs[qbase + 16 + lq] - aq0);   // <=0 arg, safe
      #pragma unroll
      for (int kk=0; kk<2; kk++){
        const int kh = 2*t + kk;
        if (kh > j) continue;
        const int kb32  = kk*32;
        const int kbase = kh*32;
        f32x4 Sacc[2][2] = {};  // [kn][qm]
        #pragma unroll
        for (int s=0;s<2;s++){
          bf16x8 bfk[2];
          #pragma unroll
          for (int kn=0;kn<2;kn++)
            bfk[kn] = *(const bf16x8*)(Brow + (size_t)(kbase+kn*16+lq)*CONV_DIM + s*32 + quad*8);
          #pragma unroll
          for (int kn=0;kn<2;kn++)
            #pragma unroll
            for (int qm=0;qm<2;qm++)
              Sacc[kn][qm] = __builtin_amdgcn_mfma_f32_16x16x32_bf16(bfk[kn], cf[s][qm], Sacc[kn][qm], 0,0,0);
        }
        // coefficient phase, factored exps: e covers qm=0; qm=1 = e*eD
        const int ql0 = qbase + lq;
        const int ql1 = ql0 + 16;
        #pragma unroll
        for (int kn=0;kn<2;kn++){
          us4 o0, o1;
          #pragma unroll
          for (int i=0;i<4;i++){
            int kl = kbase + kn*16 + quad*4 + i;
            float e  = __expf(aq0 - acs[kl]) * dts[kl];
            float v0 = Sacc[kn][0][i] * e;
            v0 = (kl < ql0) ? v0 : ((kl == ql0) ? v0 + Dph : 0.f);
            float v1 = Sacc[kn][1][i] * (e * eD);
            v1 = (kl < ql1) ? v1 : ((kl == ql1) ? v1 + Dph : 0.f);
            o0[i] = f2bs(v0);
            o1[i] = f2bs(v1);
          }
          *(us4*)&Ms[w][(lq)*40      + kn*16 + quad*4] = o0;
          *(us4*)&Ms[w][(16+lq)*40   + kn*16 + quad*4] = o1;
        }
        asm volatile("s_waitcnt lgkmcnt(0)" ::: "memory");
        #pragma unroll
        for (int qm=0;qm<2;qm++){
          bf16x8 am = *(const bf16x8*)&Ms[w][(qm*16+lq)*40 + quad*8];
          #pragma unroll
          for (int pn=0;pn<8;pn++){
            bf16x8 bp = *(const bf16x8*)&xsT[buf][(pn*16+lq)*72 + kb32 + quad*8];
            Yacc[half][qm][pn] = __builtin_amdgcn_mfma_f32_16x16x32_bf16(bp, am, Yacc[half][qm][pn], 0,0,0);
          }
        }
      }
    }
  }

  bf16* yrow = y + (size_t)z*CHUNK*D_INNER + h*HEADDIM;
  #pragma unroll
  for (int half=0; half<2; half++){
    const int j = half ? j1 : j0;
    #pragma unroll
    for (int qm=0;qm<2;qm++){
      int q = j*32 + qm*16 + lq;
      #pragma unroll
      for (int pn=0;pn<8;pn++)
        store4(&yrow[(size_t)q*D_INNER + pn*16 + quad*4], Yacc[half][qm][pn]);
    }
  }
}

// ---------------------------------------------------------------------------
// y = y * silu(z) * rsqrt(mean(...)+eps)   (norm_w folded into Wb_out)
// ---------------------------------------------------------------------------
__global__ __launch_bounds__(256) void k_gatenorm(
    const bf16* __restrict__ zxbct, bf16* __restrict__ y){
  int m = blockIdx.x;
  int e0 = threadIdx.x*8;
  bf16x8 zv = *(const bf16x8*)(zxbct + (size_t)m*ZPAD + e0);
  bf16x8 yv = *(const bf16x8*)(y + (size_t)m*D_INNER + e0);
  float v[8]; float ss = 0.f;
  #pragma unroll
  for (int j=0;j<8;j++){
    float val = (float)yv[j] * fsilu((float)zv[j]);
    v[j] = val; ss += val*val;
  }
  #pragma unroll
  for (int off=32; off>0; off>>=1) ss += __shfl_down(ss, off, 64);
  __shared__ float red[4];
  if ((threadIdx.x & 63) == 0) red[threadIdx.x >> 6] = ss;
  __syncthreads();
  float tot = red[0]+red[1]+red[2]+red[3];
  float r = rsqrtf(tot * (1.f/D_INNER) + 1e-5f);
  bf16x8 o;
  #pragma unroll
  for (int j=0;j<8;j++) o[j] = (__bf16)(v[j] * r);
  *(bf16x8*)(y + (size_t)m*D_INNER + e0) = o;
}

extern "C" void kernel_launch(void* const* d_in, const int* in_sizes, int n_in,
                              void* d_out, int out_size, void* d_ws, size_t ws_size,
                              hipStream_t stream) {
  const float* u         = (const float*)d_in[0];
  const float* in_proj_w = (const float*)d_in[1];
  const float* conv_w    = (const float*)d_in[2];
  const float* conv_b    = (const float*)d_in[3];
  const float* dt_bias   = (const float*)d_in[4];
  const float* A_log     = (const float*)d_in[5];
  const float* Dp        = (const float*)d_in[6];
  const float* norm_w    = (const float*)d_in[7];
  const float* out_proj_w= (const float*)d_in[8];
  float* out = (float*)d_out;

  char* p = (char*)d_ws;
  auto alloc = [&](size_t bytes){ char* r = p; p += (bytes + 255) & ~size_t(255); return r; };
  bf16*  zxbct = (bf16*) alloc((size_t)MROWS*ZPAD*2);                    //  71.3 MB
  bf16*  xbc   = (bf16*) alloc((size_t)MROWS*CONV_DIM*2);                //  35.7 MB
  bf16*  y     = (bf16*) alloc((size_t)MROWS*D_INNER*2);                 //  33.6 MB
  bf16*  ub    = (bf16*) alloc((size_t)MROWS*D_MODEL*2);                 //  16.8 MB (alias: states)
  bf16*  Wb_in = (bf16*) alloc((size_t)ZPAD*D_MODEL*2);                  //   8.9 MB (alias: prevb)
  bf16*  Wb_out= (bf16*) alloc((size_t)D_MODEL*D_INNER*2);               //   4.2 MB
  float* dt_t  = (float*)alloc((size_t)NB*NHEADS*LEN*4);                 //   0.5 MB
  float* acum_t= (float*)alloc((size_t)NB*NHEADS*LEN*4);                 //   0.5 MB
  float* cd_t  = (float*)alloc((size_t)NB*NHEADS*NC*4);                  //   tiny
  float* states= (float*)ub;     // 16.8 MB, live after in_proj GEMM
  bf16*  prevb = (bf16*)Wb_in;   //  8.4 MB, live after in_proj GEMM
  // total ~171.5 MB

  dim3 blk(256);
  k_convert<<<dim3((NU4+NW14+NW24)/256), blk, 0, stream>>>(
      u, in_proj_w, out_proj_w, norm_w, ub, Wb_in, Wb_out);

  // in_proj: M=8192, N=4352, K=1024 -> grid (64, 34), m-tile fastest
  k_gemm_8w<bf16><<<dim3(64, 34), dim3(512), 0, stream>>>(
      ub, D_MODEL, Wb_in, D_MODEL, zxbct, ZPAD, D_MODEL);

  k_dt    <<<dim3(NB*NC*NHEADS), blk, 0, stream>>>(zxbct, dt_bias, A_log, dt_t, acum_t, cd_t);
  k_conv  <<<dim3(CONV_DIM/64, MROWS/64), blk, 0, stream>>>(zxbct, conv_w, conv_b, xbc);
  k_states<<<dim3(NB*NC*NHEADS), blk, 0, stream>>>(xbc, acum_t, dt_t, states);
  k_scan  <<<dim3(NB*NHEADS, 8), blk, 0, stream>>>(states, cd_t, prevb);
  k_fused <<<dim3(NB*NC*NHEADS), blk, 0, stream>>>(xbc, acum_t, dt_t, Dp, prevb, y);
  k_gatenorm<<<dim3(MROWS), blk, 0, stream>>>(zxbct, y);

  // out_proj: M=8192, N=1024, K=2048 -> grid (64, 8) = 512 blocks
  k_gemm_8w<float><<<dim3(64, 8), dim3(512), 0, stream>>>(
      y, D_INNER, Wb_out, D_INNER, out, D_MODEL, D_INNER);
}

// Round 8
// 339.626 us; speedup vs baseline: 1.0396x; 1.0396x over previous
//
#include <hip/hip_runtime.h>
#include <hip/hip_bf16.h>
#include <cstdint>
#include <cstddef>

#define D_MODEL   1024
#define D_INNER   2048
#define D_STATE   64
#define HEADDIM   128
#define NHEADS    16
#define D_CONV    4
#define CHUNK     256
#define D_IN_PROJ 4240     // 2*D_INNER + 2*D_STATE + NHEADS
#define ZPAD      4352     // padded for MFMA tiles
#define CONV_DIM  2176     // D_INNER + 2*D_STATE
#define NB        2
#define LEN       4096
#define NC        16
#define MROWS     (NB*LEN) // 8192

typedef __hip_bfloat16 bf16;
typedef __bf16 bf16x8 __attribute__((ext_vector_type(8)));
typedef float  f32x4  __attribute__((ext_vector_type(4)));
typedef unsigned short us4 __attribute__((ext_vector_type(4)));

__device__ __forceinline__ float fsilu(float x){ return x / (1.f + __expf(-x)); }
__device__ __forceinline__ float toF(float x){ return x; }
__device__ __forceinline__ float toF(bf16 x){ return __bfloat162float(x); }

__device__ __forceinline__ unsigned short f2bs(float v){
  return __bfloat16_as_ushort(__float2bfloat16(v));
}
__device__ __forceinline__ void store4(bf16* p, f32x4 v){
  us4 o; o[0]=f2bs(v[0]); o[1]=f2bs(v[1]); o[2]=f2bs(v[2]); o[3]=f2bs(v[3]);
  *(us4*)p = o;
}
__device__ __forceinline__ void store4(float* p, f32x4 v){
  *(f32x4*)p = v;
}

__device__ __forceinline__ void gload_lds16(const void* g, void* l){
  __builtin_amdgcn_global_load_lds(
     (const __attribute__((address_space(1))) unsigned int*)(uintptr_t)g,
     (__attribute__((address_space(3))) unsigned int*)(uintptr_t)l, 16, 0, 0);
}

// ---------------------------------------------------------------------------
// GEMM variant A (in_proj): 8-wave pipeline, measured best for GEMM1
// (92.4/91.6us across R6/R7 vs 96.0 for the 4-wave form).
// BK=64, 2x32KB double buffer, counted vmcnt(4), 512 thr = 8 waves (2M x 4N,
// 64x32/wave), sigma(row)=row&7 both-sides swizzle (0 conflicts), plain 2D
// grid m-fastest (per-XCD A slice L2-resident, ~62MB FETCH).
// ---------------------------------------------------------------------------
template<typename TC>
__global__ __launch_bounds__(512) void k_gemm_8w(
    const bf16* __restrict__ A, int lda,
    const bf16* __restrict__ B, int ldb,
    TC* __restrict__ C, int ldc, int K)
{
  __shared__ __align__(16) __bf16 As[2][128*64];   // 16KB per buffer
  __shared__ __align__(16) __bf16 Bs[2][128*64];
  const int tid  = threadIdx.x;
  const int w    = tid >> 6, l = tid & 63;
  const int quad = l >> 4, lq = l & 15;
  const int wm   = (w & 1)*64;        // 2 M-wave positions (64 rows)
  const int wn   = (w >> 1)*32;       // 4 N-wave positions (32 rows)
  const int m0 = blockIdx.x*128, n0 = blockIdx.y*128;

  // staging source map (chunk = tid on instr0, row +64 on instr1)
  const int sr = tid >> 3;                         // row 0..63
  const int sc = ((tid & 7) ^ (sr & 7)) * 8;       // element col (16B slots)
  const bf16* Ag = A + (size_t)(m0 + sr)*lda + sc;
  const bf16* Bg = B + (size_t)(n0 + sr)*ldb + sc;
  const int sdo = w*1024;                          // wave-uniform LDS offset

  auto stage = [&](int t, int buf){
    const int k0 = t*64;
    char* ab = (char*)&As[buf][0] + sdo;
    char* bb = (char*)&Bs[buf][0] + sdo;
    gload_lds16(Ag + k0,                  ab);
    gload_lds16(Ag + (size_t)64*lda + k0, ab + 8192);
    gload_lds16(Bg + k0,                  bb);
    gload_lds16(Bg + (size_t)64*ldb + k0, bb + 8192);
  };

  f32x4 acc[4][2] = {};

  stage(0, 0);
  const int NT = K >> 6;
  for (int t = 0; t < NT; ++t){
    const int cur = t & 1;
    if (t+1 < NT){
      stage(t+1, cur^1);
      asm volatile("s_waitcnt vmcnt(4)" ::: "memory");   // tile t's 4 landed
    } else {
      asm volatile("s_waitcnt vmcnt(0)" ::: "memory");
    }
    asm volatile("s_barrier" ::: "memory");

    const char* Ab = (const char*)&As[cur][0];
    const char* Bb = (const char*)&Bs[cur][0];
    #pragma unroll
    for (int s=0;s<2;s++){
      const int slot = (((s*4 + quad) ^ (lq & 7)) << 4);
      bf16x8 af[4], bfr[2];
      #pragma unroll
      for (int tm=0;tm<4;tm++)
        af[tm]  = *(const bf16x8*)(Ab + (wm + tm*16 + lq)*128 + slot);
      #pragma unroll
      for (int tn=0;tn<2;tn++)
        bfr[tn] = *(const bf16x8*)(Bb + (wn + tn*16 + lq)*128 + slot);
      #pragma unroll
      for (int tm=0;tm<4;tm++)
        #pragma unroll
        for (int tn=0;tn<2;tn++)
          acc[tm][tn] = __builtin_amdgcn_mfma_f32_16x16x32_bf16(bfr[tn], af[tm], acc[tm][tn], 0,0,0);
    }
    asm volatile("s_barrier" ::: "memory");   // reads of cur done before t+2 stages into it
  }

  #pragma unroll
  for (int tm = 0; tm < 4; tm++){
    int r = m0 + wm + tm*16 + lq;
    #pragma unroll
    for (int tn = 0; tn < 2; tn++){
      int cb = n0 + wn + tn*16 + quad*4;
      store4(&C[(size_t)r*ldc + cb], acc[tm][tn]);
    }
  }
}

// ---------------------------------------------------------------------------
// GEMM variant B (out_proj): round-4 4-wave form, restored verbatim (the
// configuration present in the best measured total, 344.4us).  BK=64,
// 2x32KB dbuf, counted vmcnt(8), 256 thr = 4 waves of 64x64.
// ---------------------------------------------------------------------------
template<typename TC>
__global__ __launch_bounds__(256) void k_gemm_db(
    const bf16* __restrict__ A, int lda,
    const bf16* __restrict__ B, int ldb,
    TC* __restrict__ C, int ldc, int K)
{
  __shared__ __align__(16) __bf16 As[2][128*64];   // 16KB per buffer
  __shared__ __align__(16) __bf16 Bs[2][128*64];
  const int tid  = threadIdx.x;
  const int w    = tid >> 6, l = tid & 63;
  const int quad = l >> 4, lq = l & 15;
  const int wm   = (w & 1)*64, wn = (w >> 1)*64;
  const int m0 = blockIdx.x*128, n0 = blockIdx.y*128;

  const int rs = w*8 + (l >> 3);
  const int cs = ((l & 7) ^ (l >> 3)) * 8;
  const bf16* Ag = A + (size_t)(m0 + rs)*lda + cs;
  const bf16* Bg = B + (size_t)(n0 + rs)*ldb + cs;

  auto stage = [&](int t, int buf){
    const int k0 = t*64;
    #pragma unroll
    for (int j=0;j<4;j++){
      gload_lds16(Ag + (size_t)j*32*lda + k0, (char*)&As[buf][0] + (j*32 + w*8)*128);
      gload_lds16(Bg + (size_t)j*32*ldb + k0, (char*)&Bs[buf][0] + (j*32 + w*8)*128);
    }
  };

  f32x4 acc[4][4] = {};

  stage(0, 0);
  const int NT = K >> 6;
  for (int t = 0; t < NT; ++t){
    const int cur = t & 1;
    if (t+1 < NT){
      stage(t+1, cur^1);
      asm volatile("s_waitcnt vmcnt(8)" ::: "memory");   // tile t's 8 landed
    } else {
      asm volatile("s_waitcnt vmcnt(0)" ::: "memory");
    }
    asm volatile("s_barrier" ::: "memory");

    const char* Ab = (const char*)&As[cur][0];
    const char* Bb = (const char*)&Bs[cur][0];
    #pragma unroll
    for (int s=0;s<2;s++){
      const int slot = ((s*4 + quad) ^ (lq & 7)) << 4;
      bf16x8 af[4], bfr[4];
      #pragma unroll
      for (int tm=0;tm<4;tm++)
        af[tm]  = *(const bf16x8*)(Ab + (wm + lq + tm*16)*128 + slot);
      #pragma unroll
      for (int tn=0;tn<4;tn++)
        bfr[tn] = *(const bf16x8*)(Bb + (wn + lq + tn*16)*128 + slot);
      #pragma unroll
      for (int tm=0;tm<4;tm++)
        #pragma unroll
        for (int tn=0;tn<4;tn++)
          acc[tm][tn] = __builtin_amdgcn_mfma_f32_16x16x32_bf16(bfr[tn], af[tm], acc[tm][tn], 0,0,0);
    }
    asm volatile("s_barrier" ::: "memory");   // all reads of cur done before t+2 stages into it
  }

  #pragma unroll
  for (int tm = 0; tm < 4; tm++){
    int r = m0 + wm + tm*16 + lq;
    #pragma unroll
    for (int tn = 0; tn < 4; tn++){
      int cb = n0 + wn + tn*16 + quad*4;
      store4(&C[(size_t)r*ldc + cb], acc[tm][tn]);
    }
  }
}

// ---------------------------------------------------------------------------
// Fused conversions: u->ub ; in_proj_w->Wb_in (padded) ; out_proj_w*norm_w->Wb_out
// ---------------------------------------------------------------------------
#define NU4  (MROWS*D_MODEL/4)
#define NW14 (ZPAD*D_MODEL/4)
#define NW24 (D_MODEL*D_INNER/4)
__global__ __launch_bounds__(256) void k_convert(
    const float* __restrict__ u, const float* __restrict__ Win,
    const float* __restrict__ Wout, const float* __restrict__ norm_w,
    bf16* __restrict__ ub, bf16* __restrict__ Wb_in, bf16* __restrict__ Wb_out){
  int i4 = blockIdx.x*256 + threadIdx.x;
  if (i4 < NU4){
    float4 v = ((const float4*)u)[i4];
    us4 o = {f2bs(v.x), f2bs(v.y), f2bs(v.z), f2bs(v.w)};
    ((us4*)ub)[i4] = o;
  } else if (i4 < NU4 + NW14){
    int j = i4 - NU4;
    int r = j >> 8;
    float4 v = make_float4(0.f,0.f,0.f,0.f);
    if (r < D_IN_PROJ) v = ((const float4*)Win)[j];
    us4 o = {f2bs(v.x), f2bs(v.y), f2bs(v.z), f2bs(v.w)};
    ((us4*)Wb_in)[j] = o;
  } else {
    int j = i4 - NU4 - NW14;
    float4 v = ((const float4*)Wout)[j];
    float4 nw = ((const float4*)norm_w)[j & 511];
    us4 o = {f2bs(v.x*nw.x), f2bs(v.y*nw.y), f2bs(v.z*nw.z), f2bs(v.w*nw.w)};
    ((us4*)Wb_out)[j] = o;
  }
}

// ---------------------------------------------------------------------------
// dt = softplus(dt_raw + dt_bias); a = dt*A; inclusive cumsum over chunk.
// ---------------------------------------------------------------------------
__global__ __launch_bounds__(256) void k_dt(
    const bf16* __restrict__ zxbct, const float* __restrict__ dt_bias,
    const float* __restrict__ A_log, float* __restrict__ dt_t,
    float* __restrict__ acum_t, float* __restrict__ cd_t){
  int bid = blockIdx.x;
  int h = bid & 15, c = (bid>>4)&15, b = bid>>8;
  int q = threadIdx.x;
  size_t m = (size_t)(b*NC + c)*CHUNK + q;
  float x = toF(zxbct[m*ZPAD + (D_INNER + CONV_DIM) + h]) + dt_bias[h];
  float dtv = (x > 20.f) ? x : log1pf(__expf(x));
  float Ah = -__expf(A_log[h]);
  float a = dtv * Ah;
  __shared__ float sb[CHUNK];
  sb[q] = a;
  __syncthreads();
  #pragma unroll
  for (int off=1; off<CHUNK; off<<=1){
    float t = (q >= off) ? sb[q-off] : 0.f;
    __syncthreads();
    sb[q] += t;
    __syncthreads();
  }
  float ac = sb[q];
  size_t o = ((size_t)(b*NHEADS+h))*LEN + c*CHUNK + q;
  dt_t[o]   = dtv;
  acum_t[o] = ac;
  if (q == CHUNK-1) cd_t[(b*NHEADS+h)*NC + c] = __expf(ac);
}

// ---------------------------------------------------------------------------
// Depthwise causal conv (4 taps) + SiLU, LDS-staged.  64 ch x 64 rows/block.
// ---------------------------------------------------------------------------
__global__ __launch_bounds__(256) void k_conv(
    const bf16* __restrict__ zxbct, const float* __restrict__ conv_w,
    const float* __restrict__ conv_b, bf16* __restrict__ xbc){
  __shared__ __align__(16) __bf16 xs[67*64];
  __shared__ __align__(16) float  ws[64*4];
  __shared__ float bs[64];
  const int tid = threadIdx.x;
  const int cq = tid & 7;
  const int tm = tid >> 3;          // 0..31
  const int c0 = blockIdx.x*64;
  const int m0 = blockIdx.y*64;
  {
    int g = m0 - 3 + tm; if (g < 0) g = 0;
    *(bf16x8*)&xs[tm*64 + cq*8] =
        *(const bf16x8*)(zxbct + (size_t)g*ZPAD + D_INNER + c0 + cq*8);
    int g2 = m0 - 3 + tm + 32;
    *(bf16x8*)&xs[(tm+32)*64 + cq*8] =
        *(const bf16x8*)(zxbct + (size_t)g2*ZPAD + D_INNER + c0 + cq*8);
    if (tid < 24){
      int r3 = 64 + (tid >> 3);
      int g3 = m0 - 3 + r3;
      *(bf16x8*)&xs[r3*64 + cq*8] =
          *(const bf16x8*)(zxbct + (size_t)g3*ZPAD + D_INNER + c0 + cq*8);
    }
  }
  if (tid < 64)      *(float4*)&ws[tid*4] = *(const float4*)(conv_w + (size_t)(c0+tid)*4);
  else if (tid < 128) bs[tid-64] = conv_b[c0 + tid - 64];
  __syncthreads();

  #pragma unroll
  for (int rr=0; rr<2; rr++){
    const int r = tm + rr*32;
    const int m = m0 + r;
    const int l = m & (LEN-1);
    float acc[8];
    #pragma unroll
    for (int j=0;j<8;j++) acc[j] = bs[cq*8+j];
    #pragma unroll
    for (int w=0; w<D_CONV; w++){
      if (l - (D_CONV-1) + w >= 0){
        bf16x8 v = *(const bf16x8*)&xs[(r+w)*64 + cq*8];
        #pragma unroll
        for (int j=0;j<8;j++) acc[j] += (float)v[j] * ws[(cq*8+j)*4 + w];
      }
    }
    bf16x8 o;
    #pragma unroll
    for (int j=0;j<8;j++) o[j] = (__bf16)fsilu(acc[j]);
    *(bf16x8*)(xbc + (size_t)m*CONV_DIM + c0 + cq*8) = o;
  }
}

// ---------------------------------------------------------------------------
// k_states per (b,c,h): states[p,n] = sum_q dt[q]*exp(alast-acum[q])*x[q,p]*B[q,n]
// Double-buffered transposed staging, 1 barrier per k-tile.
// ---------------------------------------------------------------------------
__global__ __launch_bounds__(256,2) void k_states(
    const bf16* __restrict__ xbc, const float* __restrict__ acum_t,
    const float* __restrict__ dt_t, float* __restrict__ states)
{
  const int bid = blockIdx.x;
  const int h = bid & 15, c = (bid>>4)&15, b = bid>>8;
  const int z = b*NC + c;
  const int tid = threadIdx.x;
  const int w = tid >> 6, l = tid & 63;
  const int quad = l >> 4, lq = l & 15;

  __shared__ __align__(16) __bf16 xsT[2][128*72];
  __shared__ __align__(16) __bf16 bts[2][64*72];

  const float* acum = acum_t + ((size_t)(b*NHEADS+h))*LEN + c*CHUNK;
  const float* dtc  = dt_t   + ((size_t)(b*NHEADS+h))*LEN + c*CHUNK;
  const float alast = acum[CHUNK-1];
  const bf16* xrow = xbc + (size_t)z*CHUNK*CONV_DIM + h*HEADDIM;
  const bf16* Brow = xbc + (size_t)z*CHUNK*CONV_DIM + D_INNER;

  f32x4 Sst[2][4] = {};

  auto stage = [&](int t, int buf){
    const int k0 = t*64;
    const bf16* xr = xrow + (size_t)(k0+l)*CONV_DIM;
    #pragma unroll
    for (int pass=0; pass<4; pass++){
      int pb = w*8 + pass*32;
      bf16x8 v = *(const bf16x8*)(xr + pb);
      #pragma unroll
      for (int j=0;j<8;j++) xsT[buf][(pb+j)*72 + l] = v[j];
    }
    float wl = dtc[k0+l] * __expf(alast - acum[k0+l]);
    const bf16* br = Brow + (size_t)(k0+l)*CONV_DIM;
    #pragma unroll
    for (int pass=0; pass<2; pass++){
      int nb = w*8 + pass*32;
      bf16x8 v = *(const bf16x8*)(br + nb);
      #pragma unroll
      for (int j=0;j<8;j++) bts[buf][(nb+j)*72 + l] = (__bf16)((float)v[j] * wl);
    }
  };

  stage(0, 0);
  for (int t = 0; t < 4; t++){
    const int buf = t & 1;
    __syncthreads();
    if (t < 3) stage(t+1, buf^1);
    #pragma unroll
    for (int s=0;s<2;s++){
      bf16x8 a2[2];
      #pragma unroll
      for (int mi=0;mi<2;mi++)
        a2[mi] = *(const bf16x8*)&xsT[buf][(w*32 + mi*16 + lq)*72 + s*32 + quad*8];
      #pragma unroll
      for (int ni=0;ni<4;ni++){
        bf16x8 bb = *(const bf16x8*)&bts[buf][(ni*16+lq)*72 + s*32 + quad*8];
        #pragma unroll
        for (int mi=0;mi<2;mi++)
          Sst[mi][ni] = __builtin_amdgcn_mfma_f32_16x16x32_bf16(bb, a2[mi], Sst[mi][ni], 0,0,0);
      }
    }
  }

  float* so = states + (size_t)bid*HEADDIM*D_STATE;
  #pragma unroll
  for (int mi=0;mi<2;mi++){
    int pp = w*32 + mi*16 + lq;
    #pragma unroll
    for (int ni=0;ni<4;ni++)
      store4(&so[pp*D_STATE + ni*16 + quad*4], Sst[mi][ni]);
  }
}

// ---------------------------------------------------------------------------
// Inter-chunk scan: prevb[c] = bf16(carry); carry = carry*cd + states[c]
// ---------------------------------------------------------------------------
__global__ __launch_bounds__(256) void k_scan(
    const float* __restrict__ states, const float* __restrict__ cd_t,
    bf16* __restrict__ prevb){
  int b = blockIdx.x >> 4, h = blockIdx.x & 15;
  int pt = blockIdx.y;
  int tid = threadIdx.x;
  float carry[4] = {0.f,0.f,0.f,0.f};
  for (int c=0;c<NC;c++){
    size_t base = ((size_t)(b*256 + c*16 + h))*HEADDIM*D_STATE + (size_t)pt*1024;
    float cd = cd_t[(b*NHEADS+h)*NC + c];
    #pragma unroll
    for (int i=0;i<4;i++){
      size_t idx = base + (size_t)i*256 + tid;
      prevb[idx] = __float2bfloat16(carry[i]);
      carry[i] = carry[i]*cd + states[idx];
    }
  }
}

// ---------------------------------------------------------------------------
// FUSED per (b,c,h): y = y_off (from prevb) + y_diag (scores->coef->PV) + x*Dp.
// Single write of y.  Balanced causal split (wave w owns q half-tiles w, 7-w).
// Double-buffered x^T staging, 1 barrier per k-tile.
// ROUND 8: restored verbatim to the round-4 form (the best measured total).
// Both the R5/R6 cfh register hoist and the R7 exp-factoring restructure
// measured as regressions (+5.4 and +6.9us respectively) -- the compiler's
// schedule here is fragile; do not perturb without an ablation harness.
// ---------------------------------------------------------------------------
__global__ __launch_bounds__(256,2) void k_fused(
    const bf16* __restrict__ xbc, const float* __restrict__ acum_t,
    const float* __restrict__ dt_t, const float* __restrict__ Dp,
    const bf16* __restrict__ prevb, bf16* __restrict__ y)
{
  const int bid = blockIdx.x;
  const int h = bid & 15, c = (bid>>4)&15, b = bid>>8;
  const int z = b*NC + c;
  const int tid = threadIdx.x;
  const int w = tid >> 6, l = tid & 63;
  const int quad = l >> 4, lq = l & 15;

  __shared__ __align__(16) __bf16 xsT[2][128*72];   // [p][k64] double-buffered
  __shared__ __align__(16) __bf16 Ms[4][32*40];     // per-wave coef [q32][k32]
  __shared__ float acs[CHUNK], dts[CHUNK];

  const float* acum = acum_t + ((size_t)(b*NHEADS+h))*LEN + c*CHUNK;
  const float* dtc  = dt_t   + ((size_t)(b*NHEADS+h))*LEN + c*CHUNK;
  acs[tid] = acum[tid];
  dts[tid] = dtc[tid];

  const bf16* xrow = xbc + (size_t)z*CHUNK*CONV_DIM + h*HEADDIM;
  const bf16* Brow = xbc + (size_t)z*CHUNK*CONV_DIM + D_INNER;
  const bf16* Crow = xbc + (size_t)z*CHUNK*CONV_DIM + D_INNER + D_STATE;
  const bf16* pv   = prevb + (size_t)bid*HEADDIM*D_STATE;
  const float Dph = Dp[h];
  const int j0 = w, j1 = 7 - w;

  f32x4 Yacc[2][2][8] = {};   // [half][qm][pn]; lane: q=lq, p=quad*4+i

  auto stage = [&](int t, int buf){
    const bf16* xr = xrow + (size_t)(t*64+l)*CONV_DIM;
    #pragma unroll
    for (int pass=0; pass<4; pass++){
      int pb = w*8 + pass*32;
      bf16x8 v = *(const bf16x8*)(xr + pb);
      #pragma unroll
      for (int j=0;j<8;j++) xsT[buf][(pb+j)*72 + l] = v[j];
    }
  };

  stage(0, 0);
  __syncthreads();   // covers acs/dts too

  // ---- y_off: Yacc += mfma(prevb p-rows, exp(acum_q)*C q-rows)
  #pragma unroll
  for (int s=0;s<2;s++){
    bf16x8 bp[8];
    #pragma unroll
    for (int pn=0;pn<8;pn++)
      bp[pn] = *(const bf16x8*)(pv + (pn*16+lq)*D_STATE + s*32 + quad*8);
    #pragma unroll
    for (int half=0; half<2; half++){
      const int j = half ? j1 : j0;
      #pragma unroll
      for (int qm=0;qm<2;qm++){
        int row = j*32 + qm*16 + lq;
        float e = __expf(acs[row]);
        bf16x8 a = *(const bf16x8*)(Crow + (size_t)row*CONV_DIM + s*32 + quad*8);
        bf16x8 ae;
        #pragma unroll
        for (int jj=0;jj<8;jj++) ae[jj] = (__bf16)((float)a[jj] * e);
        #pragma unroll
        for (int pn=0;pn<8;pn++)
          Yacc[half][qm][pn] = __builtin_amdgcn_mfma_f32_16x16x32_bf16(bp[pn], ae, Yacc[half][qm][pn], 0,0,0);
      }
    }
  }

  for (int t = 0; t < 4; t++){
    const int buf = t & 1;
    if (t > 0) __syncthreads();
    if (t < 3) stage(t+1, buf^1);

    #pragma unroll
    for (int half=0; half<2; half++){
      const int j = half ? j1 : j0;
      if (2*t > j) continue;
      const int qbase = j*32;
      bf16x8 cf[2][2];   // [s][qm]
      #pragma unroll
      for (int s=0;s<2;s++)
        #pragma unroll
        for (int qm=0;qm<2;qm++)
          cf[s][qm] = *(const bf16x8*)(Crow + (size_t)(qbase+qm*16+lq)*CONV_DIM + s*32 + quad*8);
      #pragma unroll
      for (int kk=0; kk<2; kk++){
        const int kh = 2*t + kk;
        if (kh > j) continue;
        const int kb32  = kk*32;
        const int kbase = kh*32;
        f32x4 Sacc[2][2] = {};  // [kn][qm]
        #pragma unroll
        for (int s=0;s<2;s++){
          bf16x8 bfk[2];
          #pragma unroll
          for (int kn=0;kn<2;kn++)
            bfk[kn] = *(const bf16x8*)(Brow + (size_t)(kbase+kn*16+lq)*CONV_DIM + s*32 + quad*8);
          #pragma unroll
          for (int kn=0;kn<2;kn++)
            #pragma unroll
            for (int qm=0;qm<2;qm++)
              Sacc[kn][qm] = __builtin_amdgcn_mfma_f32_16x16x32_bf16(bfk[kn], cf[s][qm], Sacc[kn][qm], 0,0,0);
        }
        #pragma unroll
        for (int qm=0;qm<2;qm++){
          int ql = qbase + qm*16 + lq;
          float aq = acs[ql];
          #pragma unroll
          for (int kn=0;kn<2;kn++){
            us4 o;
            #pragma unroll
            for (int i=0;i<4;i++){
              int kl = kbase + kn*16 + quad*4 + i;
              float v = Sacc[kn][qm][i] * __expf(aq - acs[kl]) * dts[kl];
              v = (kl < ql) ? v : ((kl == ql) ? v + Dph : 0.f);
              o[i] = f2bs(v);
            }
            *(us4*)&Ms[w][(qm*16+lq)*40 + kn*16 + quad*4] = o;
          }
        }
        asm volatile("s_waitcnt lgkmcnt(0)" ::: "memory");
        #pragma unroll
        for (int qm=0;qm<2;qm++){
          bf16x8 am = *(const bf16x8*)&Ms[w][(qm*16+lq)*40 + quad*8];
          #pragma unroll
          for (int pn=0;pn<8;pn++){
            bf16x8 bp = *(const bf16x8*)&xsT[buf][(pn*16+lq)*72 + kb32 + quad*8];
            Yacc[half][qm][pn] = __builtin_amdgcn_mfma_f32_16x16x32_bf16(bp, am, Yacc[half][qm][pn], 0,0,0);
          }
        }
      }
    }
  }

  bf16* yrow = y + (size_t)z*CHUNK*D_INNER + h*HEADDIM;
  #pragma unroll
  for (int half=0; half<2; half++){
    const int j = half ? j1 : j0;
    #pragma unroll
    for (int qm=0;qm<2;qm++){
      int q = j*32 + qm*16 + lq;
      #pragma unroll
      for (int pn=0;pn<8;pn++)
        store4(&yrow[(size_t)q*D_INNER + pn*16 + quad*4], Yacc[half][qm][pn]);
    }
  }
}

// ---------------------------------------------------------------------------
// y = y * silu(z) * rsqrt(mean(...)+eps)   (norm_w folded into Wb_out)
// ---------------------------------------------------------------------------
__global__ __launch_bounds__(256) void k_gatenorm(
    const bf16* __restrict__ zxbct, bf16* __restrict__ y){
  int m = blockIdx.x;
  int e0 = threadIdx.x*8;
  bf16x8 zv = *(const bf16x8*)(zxbct + (size_t)m*ZPAD + e0);
  bf16x8 yv = *(const bf16x8*)(y + (size_t)m*D_INNER + e0);
  float v[8]; float ss = 0.f;
  #pragma unroll
  for (int j=0;j<8;j++){
    float val = (float)yv[j] * fsilu((float)zv[j]);
    v[j] = val; ss += val*val;
  }
  #pragma unroll
  for (int off=32; off>0; off>>=1) ss += __shfl_down(ss, off, 64);
  __shared__ float red[4];
  if ((threadIdx.x & 63) == 0) red[threadIdx.x >> 6] = ss;
  __syncthreads();
  float tot = red[0]+red[1]+red[2]+red[3];
  float r = rsqrtf(tot * (1.f/D_INNER) + 1e-5f);
  bf16x8 o;
  #pragma unroll
  for (int j=0;j<8;j++) o[j] = (__bf16)(v[j] * r);
  *(bf16x8*)(y + (size_t)m*D_INNER + e0) = o;
}

extern "C" void kernel_launch(void* const* d_in, const int* in_sizes, int n_in,
                              void* d_out, int out_size, void* d_ws, size_t ws_size,
                              hipStream_t stream) {
  const float* u         = (const float*)d_in[0];
  const float* in_proj_w = (const float*)d_in[1];
  const float* conv_w    = (const float*)d_in[2];
  const float* conv_b    = (const float*)d_in[3];
  const float* dt_bias   = (const float*)d_in[4];
  const float* A_log     = (const float*)d_in[5];
  const float* Dp        = (const float*)d_in[6];
  const float* norm_w    = (const float*)d_in[7];
  const float* out_proj_w= (const float*)d_in[8];
  float* out = (float*)d_out;

  char* p = (char*)d_ws;
  auto alloc = [&](size_t bytes){ char* r = p; p += (bytes + 255) & ~size_t(255); return r; };
  bf16*  zxbct = (bf16*) alloc((size_t)MROWS*ZPAD*2);                    //  71.3 MB
  bf16*  xbc   = (bf16*) alloc((size_t)MROWS*CONV_DIM*2);                //  35.7 MB
  bf16*  y     = (bf16*) alloc((size_t)MROWS*D_INNER*2);                 //  33.6 MB
  bf16*  ub    = (bf16*) alloc((size_t)MROWS*D_MODEL*2);                 //  16.8 MB (alias: states)
  bf16*  Wb_in = (bf16*) alloc((size_t)ZPAD*D_MODEL*2);                  //   8.9 MB (alias: prevb)
  bf16*  Wb_out= (bf16*) alloc((size_t)D_MODEL*D_INNER*2);               //   4.2 MB
  float* dt_t  = (float*)alloc((size_t)NB*NHEADS*LEN*4);                 //   0.5 MB
  float* acum_t= (float*)alloc((size_t)NB*NHEADS*LEN*4);                 //   0.5 MB
  float* cd_t  = (float*)alloc((size_t)NB*NHEADS*NC*4);                  //   tiny
  float* states= (float*)ub;     // 16.8 MB, live after in_proj GEMM
  bf16*  prevb = (bf16*)Wb_in;   //  8.4 MB, live after in_proj GEMM
  // total ~171.5 MB

  dim3 blk(256);
  k_convert<<<dim3((NU4+NW14+NW24)/256), blk, 0, stream>>>(
      u, in_proj_w, out_proj_w, norm_w, ub, Wb_in, Wb_out);

  // in_proj: M=8192, N=4352, K=1024 -> grid (64, 34), 8-wave variant
  k_gemm_8w<bf16><<<dim3(64, 34), dim3(512), 0, stream>>>(
      ub, D_MODEL, Wb_in, D_MODEL, zxbct, ZPAD, D_MODEL);

  k_dt    <<<dim3(NB*NC*NHEADS), blk, 0, stream>>>(zxbct, dt_bias, A_log, dt_t, acum_t, cd_t);
  k_conv  <<<dim3(CONV_DIM/64, MROWS/64), blk, 0, stream>>>(zxbct, conv_w, conv_b, xbc);
  k_states<<<dim3(NB*NC*NHEADS), blk, 0, stream>>>(xbc, acum_t, dt_t, states);
  k_scan  <<<dim3(NB*NHEADS, 8), blk, 0, stream>>>(states, cd_t, prevb);
  k_fused <<<dim3(NB*NC*NHEADS), blk, 0, stream>>>(xbc, acum_t, dt_t, Dp, prevb, y);
  k_gatenorm<<<dim3(MROWS), blk, 0, stream>>>(zxbct, y);

  // out_proj: M=8192, N=1024, K=2048 -> grid (64, 8), round-4 4-wave variant
  k_gemm_db<float><<<dim3(64, 8), blk, 0, stream>>>(
      y, D_INNER, Wb_out, D_INNER, out, D_MODEL, D_INNER);
}